// Round 10
// baseline (89.475 us; speedup 1.0000x reference)
//
#include <hip/hip_runtime.h>
#include <math.h>

// Problem constants: B=64, IN=1024, OUT=512, T=512, V_TH=1, TAU=16
#define BATCH   64
#define INS     1024
#define OUTS    512
#define TSTEPS  512
#define TAUF    16.0f
#define LOG2E_OVER_TAU 0.0901684400555602f

typedef unsigned int u32;

// ---------------------------------------------------------------------------
// Pre-kernel: blocks [0,512) 32x32 tiled transpose w[OUT,IN]->wT[IN,OUT];
// blocks [512,576) per-batch spike prep + counting sort by activation time.
// Record per spike (sorted): {A, int_bits(i*OUTS*4 byte off), C, t_on}.
// starts[b][tau], tau in [0,257]: # spikes with t_on < tau.
// ---------------------------------------------------------------------------
#define TT 32
#define NTRANS ((INS / TT) * (OUTS / TT))   // 512 transpose blocks

__global__ __launch_bounds__(256) void pre_kernel(
        const float* __restrict__ w, float* __restrict__ wT,
        const float* __restrict__ in_spike, float4* __restrict__ spk,
        int* __restrict__ starts) {
    __shared__ float tile[TT][TT + 1];
    __shared__ int hist[257];
    __shared__ int cursor[257];
    __shared__ int wsum[4];

    if (blockIdx.x < NTRANS) {
        const int i0 = (blockIdx.x & (INS / TT - 1)) * TT;
        const int o0 = (blockIdx.x / (INS / TT)) * TT;
        const int c  = threadIdx.x & (TT - 1);
        const int r  = threadIdx.x >> 5;          // 0..7
#pragma unroll
        for (int rr = r; rr < TT; rr += 8)
            tile[rr][c] = w[(o0 + rr) * INS + i0 + c];
        __syncthreads();
#pragma unroll
        for (int rr = r; rr < TT; rr += 8)
            wT[(i0 + rr) * OUTS + o0 + c] = tile[c][rr];
        return;
    }

    const int b = blockIdx.x - NTRANS;
    const int tid = threadIdx.x;
    for (int k = tid; k < 257; k += 256) hist[k] = 0;
    __syncthreads();

    float sv[INS / 256];
    int   tv[INS / 256];
#pragma unroll
    for (int j = 0; j < INS / 256; ++j) {
        int i = tid + j * 256;
        float s = in_spike[b * INS + i];
        sv[j] = s;
        int t = (int)floorf(s) + 1;
        t = t < 1 ? 1 : (t > 256 ? 256 : t);
        tv[j] = t;
        atomicAdd(&hist[t], 1);
    }
    __syncthreads();

    const int lane = tid & 63;
    const int wv   = tid >> 6;
    int v = hist[tid + 1];
    int sc = v;
#pragma unroll
    for (int off = 1; off < 64; off <<= 1) {
        int n = __shfl_up(sc, off, 64);
        if (lane >= off) sc += n;
    }
    if (lane == 63) wsum[wv] = sc;
    __syncthreads();
    int base = 0;
    for (int j = 0; j < wv; ++j) base += wsum[j];
    int excl = sc + base - v;
    cursor[tid + 1] = excl;
    starts[b * 258 + tid + 1] = excl;
    if (tid == 0) { starts[b * 258] = 0; starts[b * 258 + 257] = INS; }
    __syncthreads();

#pragma unroll
    for (int j = 0; j < INS / 256; ++j) {
        int i = tid + j * 256;
        int t = tv[j];
        int pos = atomicAdd(&cursor[t], 1);
        float A = expf(fmaf(sv[j], 1.0f / TAUF, 1.0f)) * (1.0f / TAUF);
        float C = -sv[j] * A;
        // y = BYTE offset of row i in wT: i*OUTS*4
        spk[b * INS + pos] =
            make_float4(A, __int_as_float(i * (OUTS * 4)), C, __int_as_float(t));
    }
}

// ---------------------------------------------------------------------------
// Scan kernel, round-9 (resubmitted after infra failure): WS=4 snapshot
// walk, low-VGPR, XCD-localized wT.
//
// Geometry: block = (slice of 32 outputs, batch); 1024 thr = x(16 lanes,
// 2 outputs each via float2 saddr gathers) x g(64 windows of WS=4).
// blockIdx.x = SLICE (16 values): linear block id = slice + 16*batch, so
// XCD = id%8 = slice%8 -> all 64 batch-blocks of a slice live on ONE XCD
// -> its 128 KB wT slice is fetched ~once per XCD L2, not replicated x8.
//
// Register budget: 8 snapshots + 4 acc + staging ~= 50 VGPRs -> fits the
// 64-cap of __launch_bounds__(1024,8) WITHOUT spilling (R0's WS=8 carried
// 16 snapshots).  LDS 35.3 KB -> 2 blocks/CU -> 32 waves/CU TLP to ride
// out the poison-fill writeback window.
//
// Walk: per window w0=4g+1, 4 buckets pair-unrolled; after bucket d the
// scalar snapshot l_d = fma(t_d, cA, cC) (linear in running sums).  Two-
// level scan over g (8 groups of 8) -> prefix (SA,SC), totals (TA,TC).
// Check: V(t_d) = fma(t_d,SA,SC) + l_d >= exp2(t_d*log2e/tau).
// Tail [257,512): 4 steps per g via totals.  Windows+tail partition time;
// in-wave min over the 4 windows sharing x, then atomicMin -> exact.
// ---------------------------------------------------------------------------
#define OL 16            // lanes (each owns 2 outputs)
#define G  64            // time windows
#define WS 4             // steps per window (G*WS = 256 covers all t_on)
#define TAIL0 257
#define NGRP 8
#define NG (G / NGRP)    // 8 groups

__global__ __launch_bounds__(OL * G, 8) void spike_scan_kernel(
        const float4* __restrict__ spk, const int* __restrict__ starts,
        const float* __restrict__ wT, float* __restrict__ out) {
    const int slice = blockIdx.x;        // 0..15  (XCD = slice % 8)
    const int b = blockIdx.y;            // 0..63
    const int x = threadIdx.x;           // 0..15
    const int g = threadIdx.y;           // 0..63
    const int tid = g * OL + x;
    const int lane = tid & 63;

    __shared__ float4 sspk[INS];         // 16 KB
    __shared__ float4 sP[G][OL];         // 16 KB window partials (A0,C0,A1,C1)
    __shared__ float4 sQ[NG][OL];        // 2 KB group-inclusive sums
    __shared__ int    sSt[258];          // 1 KB
    __shared__ int    sFirst[2 * OL];    // 128 B

    // bulk global->LDS staging of this batch's spike stream (16 B/lane)
    {
        auto gsrc = (const __attribute__((address_space(1))) u32*)
                        (spk + (size_t)b * INS + tid);
        auto ldst = (__attribute__((address_space(3))) u32*)&sspk[tid];
        __builtin_amdgcn_global_load_lds(gsrc, ldst, 16, 0, 0);
    }
    if (tid < 258) sSt[tid] = starts[b * 258 + tid];
    if (tid < 2 * OL) sFirst[tid] = TSTEPS;
    __syncthreads();

    const int w0 = g * WS + 1;
    // SGPR byte base for this slice; per-lane 32-bit voffset = spk.y + x*8
    const char* __restrict__ wTb = (const char*)wT + (size_t)slice * (2 * OL) * 4;
    const u32 x8 = (u32)(x << 3);

    float cA0 = 0.f, cC0 = 0.f, cA1 = 0.f, cC1 = 0.f;
    float l00, l01, l02, l03;            // output 0 snapshots
    float l10, l11, l12, l13;            // output 1 snapshots
    int k = sSt[w0];

#define BUCKET(D, LA, LB)                                                     \
    {                                                                         \
        const int e = sSt[w0 + (D) + 1];                                      \
        for (; k + 2 <= e; k += 2) {                                          \
            float4 p0 = sspk[k + 0];                                          \
            float4 p1 = sspk[k + 1];                                          \
            float2 q0 = *(const float2*)(wTb + ((u32)__float_as_int(p0.y) + x8)); \
            float2 q1 = *(const float2*)(wTb + ((u32)__float_as_int(p1.y) + x8)); \
            cA0 = fmaf(q0.x, p0.x, cA0); cC0 = fmaf(q0.x, p0.z, cC0);         \
            cA1 = fmaf(q0.y, p0.x, cA1); cC1 = fmaf(q0.y, p0.z, cC1);         \
            cA0 = fmaf(q1.x, p1.x, cA0); cC0 = fmaf(q1.x, p1.z, cC0);         \
            cA1 = fmaf(q1.y, p1.x, cA1); cC1 = fmaf(q1.y, p1.z, cC1);         \
        }                                                                     \
        if (k < e) {                                                          \
            float4 p = sspk[k];                                               \
            float2 q = *(const float2*)(wTb + ((u32)__float_as_int(p.y) + x8)); \
            cA0 = fmaf(q.x, p.x, cA0); cC0 = fmaf(q.x, p.z, cC0);             \
            cA1 = fmaf(q.y, p.x, cA1); cC1 = fmaf(q.y, p.z, cC1);             \
            ++k;                                                              \
        }                                                                     \
        const float tf = (float)(w0 + (D));                                   \
        LA = fmaf(tf, cA0, cC0);                                              \
        LB = fmaf(tf, cA1, cC1);                                              \
    }

    BUCKET(0, l00, l10)
    BUCKET(1, l01, l11)
    BUCKET(2, l02, l12)
    BUCKET(3, l03, l13)
#undef BUCKET

    sP[g][x] = make_float4(cA0, cC0, cA1, cC1);
    __syncthreads();

    // ---- two-level scan over g ----
    float SA0 = 0.f, SC0 = 0.f, SA1 = 0.f, SC1 = 0.f;
    {
        const int g0 = g & ~(NGRP - 1);
        for (int j = g0; j < g; ++j) {
            float4 v = sP[j][x];
            SA0 += v.x; SC0 += v.y; SA1 += v.z; SC1 += v.w;
        }
    }
    if ((g & (NGRP - 1)) == (NGRP - 1))
        sQ[g >> 3][x] = make_float4(SA0 + cA0, SC0 + cC0, SA1 + cA1, SC1 + cC1);
    __syncthreads();
    float TA0 = 0.f, TC0 = 0.f, TA1 = 0.f, TC1 = 0.f;
    {
        const int myg = g >> 3;
#pragma unroll
        for (int s = 0; s < NG; ++s) {
            float4 qv = sQ[s][x];
            TA0 += qv.x; TC0 += qv.y; TA1 += qv.z; TC1 += qv.w;
            if (s < myg) {
                SA0 += qv.x; SC0 += qv.y; SA1 += qv.z; SC1 += qv.w;
            }
        }
    }

    // ---- checks ----
    unsigned m0 = 0, m1 = 0;
#define CHECK(D, LA, LB)                                                      \
    {                                                                         \
        const float tf = (float)(w0 + (D));                                   \
        const float ev = exp2f(tf * LOG2E_OVER_TAU);                          \
        m0 |= (fmaf(tf, SA0, SC0) + (LA) >= ev) ? (1u << (D)) : 0u;           \
        m1 |= (fmaf(tf, SA1, SC1) + (LB) >= ev) ? (1u << (D)) : 0u;           \
    }
    CHECK(0, l00, l10)
    CHECK(1, l01, l11)
    CHECK(2, l02, l12)
    CHECK(3, l03, l13)
#undef CHECK
    int f0 = m0 ? (w0 + __builtin_ffs(m0) - 1) : TSTEPS;
    int f1 = m1 ? (w0 + __builtin_ffs(m1) - 1) : TSTEPS;

    // ---- spike-free tail [TAIL0, TSTEPS): 4 steps per g via totals ----
    {
        const int t0 = TAIL0 + g * WS;
        unsigned n0 = 0, n1 = 0;
        float tg = (float)t0;
#pragma unroll
        for (int d = 0; d < WS; ++d) {
            if (t0 + d < TSTEPS) {
                float ev = exp2f(tg * LOG2E_OVER_TAU);
                n0 |= (fmaf(tg, TA0, TC0) >= ev) ? (1u << d) : 0u;
                n1 |= (fmaf(tg, TA1, TC1) >= ev) ? (1u << d) : 0u;
            }
            tg += 1.0f;
        }
        if (n0) f0 = min(f0, t0 + __builtin_ffs(n0) - 1);
        if (n1) f1 = min(f1, t0 + __builtin_ffs(n1) - 1);
    }

    // in-wave min across the 4 windows sharing this x (lanes x, x+16, ...)
    f0 = min(f0, __shfl_xor(f0, 16));
    f0 = min(f0, __shfl_xor(f0, 32));
    f1 = min(f1, __shfl_xor(f1, 16));
    f1 = min(f1, __shfl_xor(f1, 32));
    if (lane < OL) {
        if (f0 < TSTEPS) atomicMin(&sFirst[2 * x], f0);
        if (f1 < TSTEPS) atomicMin(&sFirst[2 * x + 1], f1);
    }
    __syncthreads();
    if (tid < 2 * OL)
        out[b * OUTS + slice * (2 * OL) + tid] = (float)sFirst[tid];
}

// ---------------------------------------------------------------------------
extern "C" void kernel_launch(void* const* d_in, const int* in_sizes, int n_in,
                              void* d_out, int out_size, void* d_ws, size_t ws_size,
                              hipStream_t stream) {
    const float* in_spike = (const float*)d_in[0];   // [B, IN] fp32
    const float* weight   = (const float*)d_in[1];   // [OUT, IN] fp32
    float* out = (float*)d_out;                      // [B, OUT] fp32

    float*  wT     = (float*)d_ws;
    float4* spk    = (float4*)((char*)d_ws + (size_t)INS * OUTS * sizeof(float));
    int*    starts = (int*)((char*)d_ws + (size_t)INS * OUTS * sizeof(float)
                                        + (size_t)BATCH * INS * sizeof(float4));

    pre_kernel<<<NTRANS + BATCH, 256, 0, stream>>>(weight, wT, in_spike, spk, starts);
    // blockIdx.x = slice (16) so XCD = linear%8 = slice%8: slice-local L2
    spike_scan_kernel<<<dim3(OUTS / (2 * OL), BATCH), dim3(OL, G), 0, stream>>>(
        spk, starts, wT, out);
}